// Round 14
// baseline (105.861 us; speedup 1.0000x reference)
//
#include <hip/hip_runtime.h>

// Involution: B=4, C=256, H=W=56, K=7, GC=16 -> G=16, Cr=64, K2=49
// R14: R13 base + ONE change: k1 re-tiled 64o x 16px, grid (196,4)=784 blocks
//      (2x TLP at same traffic; per-block chain halved: 4 loads/thread,
//      8 MFMA/wave, 9.2 KB LDS). Staging keeps conflict-free half2 ch-pair
//      writes; each thread covers 2 chunks (cd parity), single barrier.
//      k2 byte-identical to R13 (XCD swizzle + f16 halo + transposed lw2t).
// ws: mid f16 [4][3136 px][64 c] @0 (1605632 B).

#define EPS 1e-5f

typedef __fp16 half2t __attribute__((ext_vector_type(2)));
typedef __fp16 half4t __attribute__((ext_vector_type(4)));
typedef __fp16 half8t __attribute__((ext_vector_type(8)));
typedef float floatx4 __attribute__((ext_vector_type(4)));

__device__ inline half8t pack8(float4 u0, float4 u1, float s) {
    half8t a;
    half2t q;
    q = __builtin_amdgcn_cvt_pkrtz(u0.x * s, u0.y * s); a[0] = q[0]; a[1] = q[1];
    q = __builtin_amdgcn_cvt_pkrtz(u0.z * s, u0.w * s); a[2] = q[0]; a[3] = q[1];
    q = __builtin_amdgcn_cvt_pkrtz(u1.x * s, u1.y * s); a[4] = q[0]; a[5] = q[1];
    q = __builtin_amdgcn_cvt_pkrtz(u1.z * s, u1.w * s); a[6] = q[0]; a[7] = q[1];
    return a;
}

// ---------------- Kernel 1: conv1 (1x1, 256->64) + BN + ReLU, MFMA ----------
// grid (196,4): block 64o x 16px. Thread = (c2 ch-pair, px4 quad, cd parity);
// covers chunks {cd, cd+2}; all 4 chunks staged before one barrier.
__global__ __launch_bounds__(256, 4) void k1_conv1(
    const float* __restrict__ x, const float* __restrict__ w1,
    const float* __restrict__ gamma, const float* __restrict__ beta,
    const float* __restrict__ mean, const float* __restrict__ var,
    __fp16* __restrict__ mid)
{
    __shared__ __align__(16) __fp16 lxB[4 * 16 * 72];  // [chunk][16px][72]
    const int t    = threadIdx.x;
    const int b    = blockIdx.y;
    const int p0   = blockIdx.x * 16;
    const int lane = t & 63, wvid = t >> 6;
    const int mrow = lane & 15, quad = lane >> 4;

    // staging map: ch-pair c2 0..31 (low bits: LDS 2-way-free), px-quad, parity
    const int c2 = t & 31, px4 = (t >> 5) & 3, cd = t >> 7;

    // ---- loads for chunks cd and cd+2, all in flight ----
    float4 ra[2], rb[2];
#pragma unroll
    for (int k = 0; k < 2; ++k) {
        const int ch = cd + 2 * k;
        const float* r0 = &x[(size_t)(b * 256 + ch * 64 + 2 * c2) * 3136 + p0 + px4 * 4];
        ra[k] = *(const float4*)r0;
        rb[k] = *(const float4*)(r0 + 3136);
    }

    // ---- A-fragments meanwhile: BN scale folded, f32 -> f16 (w1 L2-hot) ----
    const int orow = wvid * 16 + mrow;
    const float s = gamma[orow] * rsqrtf(var[orow] + EPS);
    half8t A[4][2];
#pragma unroll
    for (int ch = 0; ch < 4; ++ch)
#pragma unroll
        for (int h = 0; h < 2; ++h) {
            const float* src = &w1[orow * 256 + ch * 64 + h * 32 + quad * 8];
            A[ch][h] = pack8(*(const float4*)src, *(const float4*)(src + 4), s);
        }

    // ---- write both chunks to LDS (half2 ch-pairs), one barrier ----
#pragma unroll
    for (int k = 0; k < 2; ++k) {
        const int ch = cd + 2 * k;
        const float* f0 = (const float*)&ra[k];
        const float* f1 = (const float*)&rb[k];
#pragma unroll
        for (int j = 0; j < 4; ++j) {
            half2t q = __builtin_amdgcn_cvt_pkrtz(f0[j], f1[j]);
            *(half2t*)&lxB[ch * 1152 + (px4 * 4 + j) * 72 + 2 * c2] = q;
        }
    }
    __syncthreads();

    // ---- MFMA: 8 per wave ----
    floatx4 acc = {0.f, 0.f, 0.f, 0.f};
#pragma unroll
    for (int ch = 0; ch < 4; ++ch) {
        half8t bf0 = *(const half8t*)&lxB[ch * 1152 + mrow * 72 + quad * 8];
        half8t bf1 = *(const half8t*)&lxB[ch * 1152 + mrow * 72 + quad * 8 + 32];
        acc = __builtin_amdgcn_mfma_f32_16x16x32_f16(A[ch][0], bf0, acc, 0, 0, 0);
        acc = __builtin_amdgcn_mfma_f32_16x16x32_f16(A[ch][1], bf1, acc, 0, 0, 0);
    }
    __syncthreads();

    // ---- epilogue: bias + relu -> f16, transpose via lxB chunk-0 region ----
    float bb[4];
#pragma unroll
    for (int i = 0; i < 4; ++i) {
        int o = wvid * 16 + quad * 4 + i;
        float so = gamma[o] * rsqrtf(var[o] + EPS);
        bb[i] = beta[o] - mean[o] * so;
    }
#pragma unroll
    for (int i = 0; i < 4; ++i) {
        float v = fmaxf(acc[i] + bb[i], 0.f);
        lxB[mrow * 72 + wvid * 16 + quad * 4 + i] = (__fp16)v;
    }
    __syncthreads();
    {
        int px = t >> 4, o4 = t & 15;                // 256 slots = 16px x 16
        *(half4t*)&mid[(size_t)(b * 3136 + p0 + px) * 64 + o4 * 4] =
            *(const half4t*)&lxB[px * 72 + o4 * 4];
    }
}

// ---------------- Kernel 2: fused conv2 (f16 MFMA) + unfold/apply -----------
// grid: 3136 linear blocks, XCD-chunked swizzle. (byte-identical to R13)
// LDS map (bytes):
//   [0, 9216)      lmid [64px][72] f16        (GEMM phase only)
//   [0, 8960)      lxh  [16ch][14][20] f16    (halo, overlays lmid AFTER GEMM)
//   [9216, 16640)  lw2t [16pxt][232] f16      (weights, transposed stripes)
__global__ __launch_bounds__(256, 5) void k23_fused(
    const float* __restrict__ x, const __fp16* __restrict__ mid,
    const float* __restrict__ cw, const float* __restrict__ cb,
    float* __restrict__ out)
{
    __shared__ __align__(16) unsigned char smem[16640];
    __fp16* lmid = (__fp16*)smem;
    __fp16* lxh  = (__fp16*)smem;                // ch stride 280, row stride 20
    __fp16* lw2t = (__fp16*)(smem + 9216);       // [pxt][kh*32 + kw*4 + j]

    const int t  = threadIdx.x;
    const int id   = blockIdx.x;
    const int wg   = (id & 7) * 392 + (id >> 3);
    const int tile = wg % 49;
    const int pg   = wg / 49;                    // pg = b*16 + g
    const int g    = pg & 15;
    const int b    = pg >> 4;
    const int th = tile / 7, tw = tile % 7;
    const int h0 = th * 8, w0 = tw * 8;
    const int lane = t & 63, wvid = t >> 6;
    const int mrow = lane & 15, quad = lane >> 4;

    // ---- halo prefetch FIRST: 16ch x 14rows x 4 f4 (cols w0-4..w0+11) ----
    float4 rv4[4];
    int    rslot[4];
#pragma unroll
    for (int i = 0; i < 4; ++i) {
        int s = t + i * 256;
        rslot[i] = s;
        float4 v = make_float4(0.f, 0.f, 0.f, 0.f);
        if (s < 896) {
            int ch = s / 56, r = s % 56;
            int row = r >> 2, q = r & 3;
            int gh = h0 + row - 3;
            int gwb = w0 - 4 + q * 4;
            bool ok = (gh >= 0) & (gh < 56) & (gwb >= 0) & (gwb <= 52);
            int ghc = min(max(gh, 0), 55);
            int gwc = min(max(gwb, 0), 52);
            float4 ld = *(const float4*)&x[(size_t)(b * 256 + g * 16 + ch) * 3136 +
                                           ghc * 56 + gwc];
            if (ok) v = ld;
        }
        rv4[i] = v;
    }

    // A-fragments: cw f32 -> f16 inline (L2-hot); rows >=49 are zero
    const int krow = wvid * 16 + mrow;
    half8t a0 = {}, a1 = {};
    if (krow < 49) {
        const float* src = &cw[(size_t)(g * 49 + krow) * 64 + quad * 8];
        a0 = pack8(*(const float4*)src,        *(const float4*)(src + 4),  1.f);
        a1 = pack8(*(const float4*)(src + 32), *(const float4*)(src + 36), 1.f);
    }

    // stage lmid [px][c] (stride 72): contiguous-slot b128 copies
#pragma unroll
    for (int i = 0; i < 2; ++i) {
        int s  = t + i * 256;
        int px = s >> 3, c8 = s & 7;
        int pix = (h0 + (px >> 3)) * 56 + w0 + (px & 7);
        *(half8t*)&lmid[px * 72 + c8 * 8] =
            *(const half8t*)&mid[(size_t)(b * 3136 + pix) * 64 + c8 * 8];
    }
    __syncthreads();

    // MFMA GEMM: D[ko][px] -> lw2t f16 transposed stripes
    {
        float bias[4];
        int   kor[4], koh[4], kow[4];
#pragma unroll
        for (int i = 0; i < 4; ++i) {
            kor[i]  = wvid * 16 + quad * 4 + i;
            koh[i]  = kor[i] / 7;
            kow[i]  = kor[i] - 7 * koh[i];
            bias[i] = (kor[i] < 49) ? cb[g * 49 + kor[i]] : 0.f;
        }
#pragma unroll
        for (int pt = 0; pt < 4; ++pt) {
            half8t b0 = *(const half8t*)&lmid[(pt * 16 + mrow) * 72 + quad * 8];
            half8t b1 = *(const half8t*)&lmid[(pt * 16 + mrow) * 72 + quad * 8 + 32];
            floatx4 acc = {0.f, 0.f, 0.f, 0.f};
            acc = __builtin_amdgcn_mfma_f32_16x16x32_f16(a0, b0, acc, 0, 0, 0);
            acc = __builtin_amdgcn_mfma_f32_16x16x32_f16(a1, b1, acc, 0, 0, 0);
            const int pb = (pt * 4 + (mrow >> 2)) * 232 + (mrow & 3);
#pragma unroll
            for (int i = 0; i < 4; ++i)
                if (kor[i] < 49)
                    lw2t[pb + koh[i] * 32 + kow[i] * 4] = (__fp16)(acc[i] + bias[i]);
        }
    }
    __syncthreads();

    // halo f4 regs -> lxh f16 [ch][row][20] (half4 stores)
#pragma unroll
    for (int i = 0; i < 4; ++i) {
        int s = rslot[i];
        if (s < 896) {
            int ch = s / 56, r = s % 56;
            int row = r >> 2, q = r & 3;
            half2t p0 = __builtin_amdgcn_cvt_pkrtz(rv4[i].x, rv4[i].y);
            half2t p1 = __builtin_amdgcn_cvt_pkrtz(rv4[i].z, rv4[i].w);
            half4t hv; hv[0] = p0[0]; hv[1] = p0[1]; hv[2] = p1[0]; hv[3] = p1[1];
            *(half4t*)&lxh[ch * 280 + row * 20 + q * 4] = hv;
        }
    }
    __syncthreads();

    // apply: thread = (cc = t>>4, 4 px); per kh: 3x half4 xr + 4x half8 wq
    const int cc = t >> 4, pxt = t & 15;
    const int sh = pxt >> 1, sw4 = (pxt & 1) * 4;
    float a0f = 0.f, a1f = 0.f, a2f = 0.f, a3f = 0.f;
#pragma unroll
    for (int kh = 0; kh < 7; ++kh) {
        const int rbh = cc * 280 + (sh + kh) * 20 + sw4;
        half4t f0 = *(const half4t*)&lxh[rbh];
        half4t f1 = *(const half4t*)&lxh[rbh + 4];
        half4t f2 = *(const half4t*)&lxh[rbh + 8];
        float xw[12];
#pragma unroll
        for (int j = 0; j < 4; ++j) {
            xw[j]     = (float)f0[j];
            xw[j + 4] = (float)f1[j];
            xw[j + 8] = (float)f2[j];
        }
        const __fp16* wb = &lw2t[pxt * 232 + kh * 32];
        half8t wv0 = *(const half8t*)(wb);
        half8t wv1 = *(const half8t*)(wb + 8);
        half8t wv2 = *(const half8t*)(wb + 16);
        half8t wv3 = *(const half8t*)(wb + 24);
#pragma unroll
        for (int kw = 0; kw < 7; ++kw) {
            __fp16 q0, q1, q2, q3;
            if (kw < 2)      { q0 = wv0[kw*4+0]; q1 = wv0[kw*4+1]; q2 = wv0[kw*4+2]; q3 = wv0[kw*4+3]; }
            else if (kw < 4) { q0 = wv1[(kw-2)*4+0]; q1 = wv1[(kw-2)*4+1]; q2 = wv1[(kw-2)*4+2]; q3 = wv1[(kw-2)*4+3]; }
            else if (kw < 6) { q0 = wv2[(kw-4)*4+0]; q1 = wv2[(kw-4)*4+1]; q2 = wv2[(kw-4)*4+2]; q3 = wv2[(kw-4)*4+3]; }
            else             { q0 = wv3[0]; q1 = wv3[1]; q2 = wv3[2]; q3 = wv3[3]; }
            a0f = fmaf((float)q0, xw[kw + 1], a0f);
            a1f = fmaf((float)q1, xw[kw + 2], a1f);
            a2f = fmaf((float)q2, xw[kw + 3], a2f);
            a3f = fmaf((float)q3, xw[kw + 4], a3f);
        }
    }
    *(float4*)&out[(size_t)(b * 256 + g * 16 + cc) * 3136 + (h0 + sh) * 56 + w0 + sw4] =
        make_float4(a0f, a1f, a2f, a3f);
}

extern "C" void kernel_launch(void* const* d_in, const int* in_sizes, int n_in,
                              void* d_out, int out_size, void* d_ws, size_t ws_size,
                              hipStream_t stream) {
    const float* x     = (const float*)d_in[0];
    const float* w1    = (const float*)d_in[1];
    const float* gamma = (const float*)d_in[2];
    const float* beta  = (const float*)d_in[3];
    const float* mean  = (const float*)d_in[4];
    const float* var   = (const float*)d_in[5];
    const float* cw    = (const float*)d_in[6];
    const float* cb    = (const float*)d_in[7];
    float* out = (float*)d_out;

    __fp16* mid = (__fp16*)d_ws;             // 1605632 B

    k1_conv1<<<dim3(196, 4), 256, 0, stream>>>(x, w1, gamma, beta, mean, var, mid);
    k23_fused<<<dim3(3136), 256, 0, stream>>>(x, mid, cw, cb, out);
}